// Round 11
// baseline (146.540 us; speedup 1.0000x reference)
//
#include <hip/hip_runtime.h>
#include <hip/hip_bf16.h>

// Problem constants
#define N_ATOMS 262144
#define B_SZ    64
#define H_DIM   256
#define R_DIM   512

#define TILE_ROWS 32
#define TPB       16                        // tiles per block
#define NBLOCKS   (N_ATOMS / (TILE_ROWS * TPB))   // 512

typedef __attribute__((ext_vector_type(8))) short bf16x8;
typedef __attribute__((ext_vector_type(4))) float f32x4;

static __device__ __forceinline__ short f2bf(float f) {
  unsigned u = __builtin_bit_cast(unsigned, f);
  u = (u + 0x7FFFu + ((u >> 16) & 1u)) >> 16;   // RNE
  return (short)u;
}

// v_cvt_pk_bf16_f32: packs 2 f32 -> 1 dword (2 bf16, RNE). No builtin on
// gfx950 (m240) — inline asm is the plain-HIP route.
static __device__ __forceinline__ unsigned cvtpk(float lo, float hi) {
  unsigned r;
  asm("v_cvt_pk_bf16_f32 %0, %1, %2" : "=v"(r) : "v"(lo), "v"(hi));
  return r;
}

static __device__ __forceinline__ bf16x8 pack8(f32x4 a0, f32x4 a1) {
  unsigned u0 = cvtpk(a0[0], a0[1]);
  unsigned u1 = cvtpk(a0[2], a0[3]);
  unsigned u2 = cvtpk(a1[0], a1[1]);
  unsigned u3 = cvtpk(a1[2], a1[3]);
  bf16x8 v;
  v[0] = (short)(u0 & 0xFFFF); v[1] = (short)(u0 >> 16);
  v[2] = (short)(u1 & 0xFFFF); v[3] = (short)(u1 >> 16);
  v[4] = (short)(u2 & 0xFFFF); v[5] = (short)(u2 >> 16);
  v[6] = (short)(u3 & 0xFFFF); v[7] = (short)(u3 >> 16);
  return v;
}

// async global->LDS DMA, 16B per lane; LDS dest = wave-uniform base + lane*16
static __device__ __forceinline__ void async_copy16(const float* g, short* lds) {
  __builtin_amdgcn_global_load_lds(
      (const __attribute__((address_space(1))) unsigned int*)g,
      (__attribute__((address_space(3))) unsigned int*)lds,
      16, 0, 0);
}

// ---------------------------------------------------------------------------
// Prep kernel (fused):
//   blocks [0,64):  pooled[b][o] = bl[o] + retj . Wl[o,256:512]
//   blocks [64,80): convert Wl[:, :256] to bf16 in MFMA fragment order:
//     Bbf[((ct*8+ks)*64+lane)*8+j] = Wl[ct*16+(lane&15)][ks*32+(lane>>4)*8+j]
// ---------------------------------------------------------------------------
__global__ __launch_bounds__(1024) void prep_kernel(
    const float* __restrict__ rf, const float* __restrict__ Wp,
    const float* __restrict__ bp, const float* __restrict__ Wl,
    const float* __restrict__ bl, float* __restrict__ pooled,
    short* __restrict__ Bbf) {
  int t = threadIdx.x;
  if (blockIdx.x >= B_SZ) {
    int base = (blockIdx.x - B_SZ) * 4096 + t * 4;
#pragma unroll
    for (int q = 0; q < 4; ++q) {
      int idx  = base + q;
      int j    = idx & 7;
      int lane = (idx >> 3) & 63;
      int ks   = (idx >> 9) & 7;
      int ct   = idx >> 12;
      int o    = ct * 16 + (lane & 15);
      int k    = ks * 32 + ((lane >> 4) << 3) + j;
      Bbf[idx] = f2bf(Wl[o * (2 * H_DIM) + k]);
    }
    return;
  }

  __shared__ float meanr[R_DIM];
  __shared__ float retj[H_DIM];
  int b    = blockIdx.x;
  int lane = t & 63;
  int w    = t >> 6;            // 16 waves

  if (t < R_DIM) {
    float s = 0.f;
    const float* p = rf + (long)b * 16 * R_DIM + t;
#pragma unroll
    for (int k = 0; k < 16; ++k) s += p[k * R_DIM];
    meanr[t] = s * (1.f / 16.f);
  }
  __syncthreads();

  {
    f32x4 m0 = *(const f32x4*)&meanr[lane * 8];
    f32x4 m1 = *(const f32x4*)&meanr[lane * 8 + 4];
#pragma unroll
    for (int jj = 0; jj < 16; ++jj) {
      int j = w * 16 + jj;
      const f32x4* wp = (const f32x4*)(Wp + (long)j * R_DIM + lane * 8);
      f32x4 w0 = wp[0], w1 = wp[1];
      float s = m0[0]*w0[0] + m0[1]*w0[1] + m0[2]*w0[2] + m0[3]*w0[3]
              + m1[0]*w1[0] + m1[1]*w1[1] + m1[2]*w1[2] + m1[3]*w1[3];
#pragma unroll
      for (int d = 1; d < 64; d <<= 1) s += __shfl_xor(s, d);
      if (lane == 0) retj[j] = s + bp[j];
    }
  }
  __syncthreads();

  {
    f32x4 r0 = *(const f32x4*)&retj[lane * 4];
#pragma unroll
    for (int oo = 0; oo < 16; ++oo) {
      int o = w * 16 + oo;
      f32x4 wv = *(const f32x4*)(Wl + (long)o * (2 * H_DIM) + H_DIM + lane * 4);
      float s = r0[0]*wv[0] + r0[1]*wv[1] + r0[2]*wv[2] + r0[3]*wv[3];
#pragma unroll
      for (int d = 1; d < 64; d <<= 1) s += __shfl_xor(s, d);
      if (lane == 0) pooled[b * H_DIM + o] = s + bl[o];
    }
  }
}

// ---------------------------------------------------------------------------
// GEMM: out[n][o] = sum_k h[n][k]*Wl[o][k] + pooled[batch[n]][o]
// 512 persistent blocks x 512 threads (8 waves), 16 tiles of 32 rows,
// double-buffered LDS (2 x 32 KiB raw f32 A-tiles) via global_load_lds.
//
// VMEM ORDER PER TILE (in-order vmcnt retirement is the whole design):
//   [6 epilogue loads: 2 batch + 4 pooled]  (oldest)
//   [4 DMAs -> As[buf^1]]
//   [4 output stores]                       (newest)
// End-of-tile sync is s_waitcnt vmcnt(4) + s_barrier: waits ONLY for the
// DMAs (next tile's data); the 4 stores keep flying across the barrier.
// No vmcnt(0) anywhere in the main loop (T4). Epilogue loads precede DMAs
// (pinned by sched_barrier) so their use-waits resolve at vmcnt(4) without
// draining the DMAs (r10's fix). Cross-wave WAR on As[buf] is protected by
// the barrier itself (no wave can issue tile t+2 DMAs into As[buf] until
// all waves finished reading As[buf] and arrived).
//
// LDS stripe S (1 KiB): lane's 16B at S*1024+lane*16 holds
// h[g0+(S>>4)*16+(lane&15)][((S>>1)&7)*32+(lane>>4)*8+(S&1)*4 ..+3]
// => DMA dest wave-uniform base + lane*16; ds_read_b128 lane-linear (0 conf).
// Wave w owns col-tiles {2w,2w+1}: B strips in registers.
// SWAPPED MFMA (bfrag first): row=lane&15, cols=ct*16+(lane>>4)*4 ->
// two adjacent dwordx4 stores per rt (full 128B lines; plain stores —
// nontemporal caused 9% write amplification in r10).
// ---------------------------------------------------------------------------
__global__ __launch_bounds__(512, 4) void gemm_kernel(
    const float* __restrict__ h, const short* __restrict__ Bbf,
    const float* __restrict__ pooled, const int* __restrict__ batch,
    float* __restrict__ out) {
  __shared__ short As[2][32 * 512];        // 2 x 32 KiB (raw f32 stripes)
  int t    = threadIdx.x;
  int lane = t & 63;
  int w    = t >> 6;                        // 0..7
  const int arow = lane & 15;
  const int kg   = lane >> 4;               // 0..3

  // --- B strips for col-tiles 2w, 2w+1 (loaded once, 64 VGPR) ---
  bf16x8 bfrag0[8], bfrag1[8];
#pragma unroll
  for (int ks = 0; ks < 8; ++ks) {
    bfrag0[ks] = *(const bf16x8*)(Bbf + ((((2 * w)     * 8 + ks) * 64 + lane) << 3));
    bfrag1[ks] = *(const bf16x8*)(Bbf + ((((2 * w + 1) * 8 + ks) * 64 + lane) << 3));
  }

  // stage geometry: wave w DMAs stripes 4w..4w+3 of a tile
  int S_[4], row_[4], col_[4];
#pragma unroll
  for (int i = 0; i < 4; ++i) {
    int S   = 4 * w + i;
    S_[i]   = S;
    row_[i] = ((S >> 4) << 4) + arow;
    col_[i] = (((S >> 1) & 7) << 5) + (kg << 3) + ((S & 1) << 2);
  }

  long base_row = (long)blockIdx.x * (TILE_ROWS * TPB);

  // --- prologue: stage tile 0 into buf 0 (full drain, once) ---
#pragma unroll
  for (int i = 0; i < 4; ++i)
    async_copy16(h + (base_row + row_[i]) * H_DIM + col_[i],
                 &As[0][S_[i] * 512]);
  __syncthreads();

  int o0 = ((2 * w) << 4) + (kg << 2);
  int o1 = o0 + 16;

  for (int tt = 0; tt < TPB; ++tt) {
    int  buf = tt & 1;
    long g0  = base_row + (long)tt * TILE_ROWS;
    bool more = (tt + 1 < TPB);

    // --- (1) epilogue VMEM loads for CURRENT tile, BEFORE any DMA issue ---
    long row0 = g0 + arow;
    long row1 = g0 + 16 + arow;
    int  b0 = batch[row0];
    int  b1 = batch[row1];
    const float* pb0 = pooled + b0 * H_DIM;
    const float* pb1 = pooled + b1 * H_DIM;
    f32x4 pv00 = *(const f32x4*)(pb0 + o0);
    f32x4 pv01 = *(const f32x4*)(pb0 + o1);
    f32x4 pv10 = *(const f32x4*)(pb1 + o0);
    f32x4 pv11 = *(const f32x4*)(pb1 + o1);
    __builtin_amdgcn_sched_barrier(0);   // pin: loads above, DMAs below

    // --- (2) stage next tile into other buffer (flies across compute) ---
    if (more) {
      long gn = g0 + TILE_ROWS;
#pragma unroll
      for (int i = 0; i < 4; ++i)
        async_copy16(h + (gn + row_[i]) * H_DIM + col_[i],
                     &As[buf ^ 1][S_[i] * 512]);
    }

    // --- (3) compute 2 row-tiles x 2 col-tiles from buf (LDS + regs only) ---
#pragma unroll
    for (int rt = 0; rt < 2; ++rt) {
      f32x4 acc0 = {0.f, 0.f, 0.f, 0.f};
      f32x4 acc1 = {0.f, 0.f, 0.f, 0.f};
#pragma unroll
      for (int ks = 0; ks < 8; ++ks) {
        int S0 = rt * 16 + ks * 2;
        f32x4 v0 = *(const f32x4*)&As[buf][(S0 * 512) + lane * 8];
        f32x4 v1 = *(const f32x4*)&As[buf][((S0 + 1) * 512) + lane * 8];
        bf16x8 af = pack8(v0, v1);
        acc0 = __builtin_amdgcn_mfma_f32_16x16x32_bf16(bfrag0[ks], af, acc0, 0, 0, 0);
        acc1 = __builtin_amdgcn_mfma_f32_16x16x32_bf16(bfrag1[ks], af, acc1, 0, 0, 0);
      }
      long row = (rt == 0) ? row0 : row1;
      f32x4 r0v = acc0 + ((rt == 0) ? pv00 : pv10);
      f32x4 r1v = acc1 + ((rt == 0) ? pv01 : pv11);
      float* orow = out + row * H_DIM;
      *(f32x4*)(orow + o0) = r0v;
      *(f32x4*)(orow + o1) = r1v;
    }

    // --- (4) counted-vmcnt barrier: wait DMAs only, stores keep flying ---
    if (more) {
      asm volatile("s_waitcnt vmcnt(4)" ::: "memory");
      __builtin_amdgcn_s_barrier();
      __builtin_amdgcn_sched_barrier(0);   // rule #18: no hoist past the wait
    }
  }
}

// ---------------------------------------------------------------------------
extern "C" void kernel_launch(void* const* d_in, const int* in_sizes, int n_in,
                              void* d_out, int out_size, void* d_ws, size_t ws_size,
                              hipStream_t stream) {
  const float* h   = (const float*)d_in[0];
  const float* rf  = (const float*)d_in[1];
  const int*   bat = (const int*)d_in[2];
  const float* Wp  = (const float*)d_in[3];
  const float* bp  = (const float*)d_in[4];
  const float* Wl  = (const float*)d_in[5];
  const float* bl  = (const float*)d_in[6];
  float* out = (float*)d_out;

  float* pooled = (float*)d_ws;                          // 64 KiB
  short* Bbf    = (short*)((char*)d_ws + 64 * 1024);     // 128 KiB

  prep_kernel<<<B_SZ + 16, 1024, 0, stream>>>(rf, Wp, bp, Wl, bl, pooled, Bbf);
  gemm_kernel<<<NBLOCKS, 512, 0, stream>>>(h, Bbf, pooled, bat, out);
}

// Round 12
// 146.088 us; speedup vs baseline: 1.0031x; 1.0031x over previous
//
#include <hip/hip_runtime.h>
#include <hip/hip_bf16.h>

// Problem constants
#define N_ATOMS 262144
#define B_SZ    64
#define H_DIM   256
#define R_DIM   512

#define TILE_ROWS 16
#define TPB       32                               // tiles per block
#define NBLOCKS   (N_ATOMS / (TILE_ROWS * TPB))    // 512
#define NBUF      4

typedef __attribute__((ext_vector_type(8))) short bf16x8;
typedef __attribute__((ext_vector_type(4))) float f32x4;

static __device__ __forceinline__ short f2bf(float f) {
  unsigned u = __builtin_bit_cast(unsigned, f);
  u = (u + 0x7FFFu + ((u >> 16) & 1u)) >> 16;   // RNE
  return (short)u;
}

// v_cvt_pk_bf16_f32 (no builtin on gfx950 — inline asm, m240)
static __device__ __forceinline__ unsigned cvtpk(float lo, float hi) {
  unsigned r;
  asm("v_cvt_pk_bf16_f32 %0, %1, %2" : "=v"(r) : "v"(lo), "v"(hi));
  return r;
}

static __device__ __forceinline__ bf16x8 pack8(f32x4 a0, f32x4 a1) {
  unsigned u0 = cvtpk(a0[0], a0[1]);
  unsigned u1 = cvtpk(a0[2], a0[3]);
  unsigned u2 = cvtpk(a1[0], a1[1]);
  unsigned u3 = cvtpk(a1[2], a1[3]);
  bf16x8 v;
  v[0] = (short)(u0 & 0xFFFF); v[1] = (short)(u0 >> 16);
  v[2] = (short)(u1 & 0xFFFF); v[3] = (short)(u1 >> 16);
  v[4] = (short)(u2 & 0xFFFF); v[5] = (short)(u2 >> 16);
  v[6] = (short)(u3 & 0xFFFF); v[7] = (short)(u3 >> 16);
  return v;
}

// async global->LDS DMA, 16B/lane; LDS dest = wave-uniform base + lane*16
static __device__ __forceinline__ void async_copy16(const float* g, short* lds) {
  __builtin_amdgcn_global_load_lds(
      (const __attribute__((address_space(1))) unsigned int*)g,
      (__attribute__((address_space(3))) unsigned int*)lds,
      16, 0, 0);
}

// ---------------------------------------------------------------------------
// Prep kernel (unchanged from r8-r11):
//   blocks [0,64):  pooled[b][o] = bl[o] + retj . Wl[o,256:512]
//   blocks [64,80): Bbf[((ct*8+ks)*64+lane)*8+j] =
//                   bf16(Wl[ct*16+(lane&15)][ks*32+(lane>>4)*8+j])
// ---------------------------------------------------------------------------
__global__ __launch_bounds__(1024) void prep_kernel(
    const float* __restrict__ rf, const float* __restrict__ Wp,
    const float* __restrict__ bp, const float* __restrict__ Wl,
    const float* __restrict__ bl, float* __restrict__ pooled,
    short* __restrict__ Bbf) {
  int t = threadIdx.x;
  if (blockIdx.x >= B_SZ) {
    int base = (blockIdx.x - B_SZ) * 4096 + t * 4;
#pragma unroll
    for (int q = 0; q < 4; ++q) {
      int idx  = base + q;
      int j    = idx & 7;
      int lane = (idx >> 3) & 63;
      int ks   = (idx >> 9) & 7;
      int ct   = idx >> 12;
      int o    = ct * 16 + (lane & 15);
      int k    = ks * 32 + ((lane >> 4) << 3) + j;
      Bbf[idx] = f2bf(Wl[o * (2 * H_DIM) + k]);
    }
    return;
  }

  __shared__ float meanr[R_DIM];
  __shared__ float retj[H_DIM];
  int b    = blockIdx.x;
  int lane = t & 63;
  int w    = t >> 6;            // 16 waves

  if (t < R_DIM) {
    float s = 0.f;
    const float* p = rf + (long)b * 16 * R_DIM + t;
#pragma unroll
    for (int k = 0; k < 16; ++k) s += p[k * R_DIM];
    meanr[t] = s * (1.f / 16.f);
  }
  __syncthreads();

  {
    f32x4 m0 = *(const f32x4*)&meanr[lane * 8];
    f32x4 m1 = *(const f32x4*)&meanr[lane * 8 + 4];
#pragma unroll
    for (int jj = 0; jj < 16; ++jj) {
      int j = w * 16 + jj;
      const f32x4* wp = (const f32x4*)(Wp + (long)j * R_DIM + lane * 8);
      f32x4 w0 = wp[0], w1 = wp[1];
      float s = m0[0]*w0[0] + m0[1]*w0[1] + m0[2]*w0[2] + m0[3]*w0[3]
              + m1[0]*w1[0] + m1[1]*w1[1] + m1[2]*w1[2] + m1[3]*w1[3];
#pragma unroll
      for (int d = 1; d < 64; d <<= 1) s += __shfl_xor(s, d);
      if (lane == 0) retj[j] = s + bp[j];
    }
  }
  __syncthreads();

  {
    f32x4 r0 = *(const f32x4*)&retj[lane * 4];
#pragma unroll
    for (int oo = 0; oo < 16; ++oo) {
      int o = w * 16 + oo;
      f32x4 wv = *(const f32x4*)(Wl + (long)o * (2 * H_DIM) + H_DIM + lane * 4);
      float s = r0[0]*wv[0] + r0[1]*wv[1] + r0[2]*wv[2] + r0[3]*wv[3];
#pragma unroll
      for (int d = 1; d < 64; d <<= 1) s += __shfl_xor(s, d);
      if (lane == 0) pooled[b * H_DIM + o] = s + bl[o];
    }
  }
}

// ---------------------------------------------------------------------------
// GEMM: out[n][o] = sum_k h[n][k]*Wl[o][k] + pooled[batch[n]][o]
// 512 persistent blocks x 512 threads (8 waves); 32 tiles of 16 rows;
// 4 LDS buffers (4 x 16 KiB raw f32) -> depth-3 DMA pipeline.
//
// Per-iter VMEM order (in-order vmcnt retirement drives everything):
//   [2 pooled(t+1) loads (b pre-loaded)] [1 batch(t+2)] [2 DMA(t+3)]
//   s_waitcnt vmcnt(9)   <- leaves DMA(t+2)+DMA(t+3)+stores(t-1)+loads(t+1)
//                           in flight; drains DMA(t+1)+pv(t)+b(t+1).
//   [compute(t): ds_read/cvt/MFMA; epilogue adds pv(t) from regs]
//   [2 stores(t)]
//   s_barrier            <- NO waitcnt: each wave's vmcnt(9) at iter t-1
//                           already drained DMA(t); barrier completes the
//                           cross-wave LDS handoff.
// => >=2 tiles of reads (32 KB/block, 64 KB/CU) in flight at EVERY point;
//    store-acks never on any wait path (1-iter slack).
// Epilogue loads pipelined 1 tile ahead, batch 2 ahead (kills the
// batch->pooled dependent-load stall).
//
// LDS stripe S in [0,16) (1 KiB each): lane's 16B at S*1024+lane*16 =
// h[g0+(lane&15)][(S>>1)*32+(lane>>4)*8+(S&1)*4 ..+3]; wave w DMAs stripes
// {2w,2w+1}. ds_read_b128 lane-linear (0 conflicts, r4/r8-verified).
// Wave w owns col-tiles {2w,2w+1}; B strips in registers (64 VGPR).
// SWAPPED MFMA: row=lane&15, cols=32w+(lane>>4)*4 (+16) -> per row the wave
// writes cols [32w,32w+32): full 128B segments, whole line per row per iter.
// ---------------------------------------------------------------------------
__global__ __launch_bounds__(512, 4) void gemm_kernel(
    const float* __restrict__ h, const short* __restrict__ Bbf,
    const float* __restrict__ pooled, const int* __restrict__ batch,
    float* __restrict__ out) {
  __shared__ short As[NBUF][16 * 512];      // 4 x 16 KiB
  int t    = threadIdx.x;
  int lane = t & 63;
  int w    = t >> 6;                         // 0..7
  const int arow = lane & 15;
  const int kg   = lane >> 4;                // 0..3

  // --- B strips for col-tiles 2w, 2w+1 (loaded once, 64 VGPR) ---
  bf16x8 bfrag0[8], bfrag1[8];
#pragma unroll
  for (int ks = 0; ks < 8; ++ks) {
    bfrag0[ks] = *(const bf16x8*)(Bbf + ((((2 * w)     * 8 + ks) * 64 + lane) << 3));
    bfrag1[ks] = *(const bf16x8*)(Bbf + ((((2 * w + 1) * 8 + ks) * 64 + lane) << 3));
  }

  long base_row = (long)blockIdx.x * (TILE_ROWS * TPB);   // 512 rows/block
  int o0 = (w << 5) + (kg << 2);                           // 32w + 4kg
  int o1 = o0 + 16;
  // per-lane global src offset within a tile (stripe pair {2w,2w+1})
  const long lsrc = (long)arow * H_DIM + (w << 5) + (kg << 3);

  // --- prologue: b(t0) -> DMA(t0) -> pv(t0) -> b(t1) -> DMA(t1,t2) ---
  int b_cur = batch[base_row + arow];
  {
    const float* gp = h + base_row * H_DIM + lsrc;
    async_copy16(gp,     &As[0][(2 * w) * 512]);
    async_copy16(gp + 4, &As[0][(2 * w + 1) * 512]);
  }
  f32x4 pv0, pv1;
  {
    const float* pb = pooled + b_cur * H_DIM;
    pv0 = *(const f32x4*)(pb + o0);
    pv1 = *(const f32x4*)(pb + o1);
  }
  int b_next = batch[base_row + TILE_ROWS + arow];
#pragma unroll
  for (int tl = 1; tl <= 2; ++tl) {
    const float* gp = h + (base_row + (long)tl * TILE_ROWS) * H_DIM + lsrc;
    async_copy16(gp,     &As[tl][(2 * w) * 512]);
    async_copy16(gp + 4, &As[tl][(2 * w + 1) * 512]);
  }
  asm volatile("s_waitcnt vmcnt(4)" ::: "memory");   // t0 landed; t1,t2 fly
  __builtin_amdgcn_s_barrier();
  __builtin_amdgcn_sched_barrier(0);

  for (int tt = 0; tt < TPB; ++tt) {
    long g0 = base_row + (long)tt * TILE_ROWS;

    // --- (1) pooled(t+1) via pre-loaded b_next ---
    f32x4 npv0 = {0.f, 0.f, 0.f, 0.f}, npv1 = {0.f, 0.f, 0.f, 0.f};
    if (tt + 1 < TPB) {
      const float* pb = pooled + b_next * H_DIM;
      npv0 = *(const f32x4*)(pb + o0);
      npv1 = *(const f32x4*)(pb + o1);
    }
    // --- (2) batch(t+2) ---
    int b_next2 = 0;
    if (tt + 2 < TPB) b_next2 = batch[g0 + 2 * TILE_ROWS + arow];
    // --- (3) DMA(t+3) ---
    if (tt + 3 < TPB) {
      const float* gp = h + (g0 + 3 * TILE_ROWS) * H_DIM + lsrc;
      short* dst = &As[(tt + 3) & 3][0];
      async_copy16(gp,     dst + (2 * w) * 512);
      async_copy16(gp + 4, dst + (2 * w + 1) * 512);
    }
    __builtin_amdgcn_sched_barrier(0);
    // --- pacing wait: drains DMA(t+1)/pv(t)/b(t+1); leaves t+2,t+3 + newer ---
    asm volatile("s_waitcnt vmcnt(9)" ::: "memory");
    __builtin_amdgcn_sched_barrier(0);

    // --- (4) compute tile t from As[tt&3] ---
    const short* ab = &As[tt & 3][0];
    f32x4 acc0 = {0.f, 0.f, 0.f, 0.f};
    f32x4 acc1 = {0.f, 0.f, 0.f, 0.f};
#pragma unroll
    for (int ks = 0; ks < 8; ++ks) {
      f32x4 v0 = *(const f32x4*)(ab + ks * 1024 + lane * 8);
      f32x4 v1 = *(const f32x4*)(ab + ks * 1024 + 512 + lane * 8);
      bf16x8 af = pack8(v0, v1);
      acc0 = __builtin_amdgcn_mfma_f32_16x16x32_bf16(bfrag0[ks], af, acc0, 0, 0, 0);
      acc1 = __builtin_amdgcn_mfma_f32_16x16x32_bf16(bfrag1[ks], af, acc1, 0, 0, 0);
    }
    // --- (5) epilogue + stores (pv from regs, loaded last iter) ---
    float* orow = out + (g0 + arow) * H_DIM;
    *(f32x4*)(orow + o0) = acc0 + pv0;
    *(f32x4*)(orow + o1) = acc1 + pv1;

    // rotate pipelined state
    pv0 = npv0; pv1 = npv1; b_next = b_next2;

    if (tt + 1 < TPB) {
      __builtin_amdgcn_s_barrier();        // no waitcnt: handoff done above
      __builtin_amdgcn_sched_barrier(0);
    }
  }
}

// ---------------------------------------------------------------------------
extern "C" void kernel_launch(void* const* d_in, const int* in_sizes, int n_in,
                              void* d_out, int out_size, void* d_ws, size_t ws_size,
                              hipStream_t stream) {
  const float* h   = (const float*)d_in[0];
  const float* rf  = (const float*)d_in[1];
  const int*   bat = (const int*)d_in[2];
  const float* Wp  = (const float*)d_in[3];
  const float* bp  = (const float*)d_in[4];
  const float* Wl  = (const float*)d_in[5];
  const float* bl  = (const float*)d_in[6];
  float* out = (float*)d_out;

  float* pooled = (float*)d_ws;                          // 64 KiB
  short* Bbf    = (short*)((char*)d_ws + 64 * 1024);     // 128 KiB

  prep_kernel<<<B_SZ + 16, 1024, 0, stream>>>(rf, Wp, bp, Wl, bl, pooled, Bbf);
  gemm_kernel<<<NBLOCKS, 512, 0, stream>>>(h, Bbf, pooled, bat, out);
}